// Round 12
// baseline (2144.984 us; speedup 1.0000x reference)
//
#include <hip/hip_runtime.h>
#include <hip/hip_bf16.h>

#define NN 100000
#define NE 1200000
#define NF 128
#define NH 64
#define NC 16
#define TILE_R 64
#define NTILES 1563     // ceil(NN/64)
#define NBUK 196        // ceil(NN/512)
#define BUKCAP 8192     // LDS sort capacity (avg 6144, 26 sigma margin)

typedef float f4v __attribute__((ext_vector_type(4)));

static __device__ __forceinline__ unsigned short f2bf(float f) {
    __hip_bfloat16 h = __float2bfloat16(f);
    return *reinterpret_cast<unsigned short*>(&h);
}
static __device__ __forceinline__ float bf2f(unsigned short u) {
    __hip_bfloat16 h = *reinterpret_cast<__hip_bfloat16*>(&u);
    return __bfloat162float(h);
}

// ---------------- CSR build: bucket -> sort ----------------
__global__ __launch_bounds__(256) void init_bcnt_kernel(int* __restrict__ bcnt) {
    if (threadIdx.x < NBUK) bcnt[threadIdx.x] = 0;
}

// per-block LDS histogram of 196 buckets
__global__ __launch_bounds__(256) void bucket_hist_kernel(const int* __restrict__ rows,
                                                          int* __restrict__ bcnt, int nthreads) {
    __shared__ int cnt[NBUK];
    const int t = threadIdx.x;
    for (int i = t; i < NBUK; i += 256) cnt[i] = 0;
    __syncthreads();
    for (int e = blockIdx.x * 256 + t; e < NE; e += nthreads) {
        int r = __builtin_nontemporal_load(&rows[e]);
        atomicAdd(&cnt[r >> 9], 1);
    }
    __syncthreads();
    for (int i = t; i < NBUK; i += 256)
        if (cnt[i]) atomicAdd(&bcnt[i], cnt[i]);
}

__global__ __launch_bounds__(256) void bucket_scan_kernel(const int* __restrict__ bcnt,
                                                          int* __restrict__ bstart,
                                                          int* __restrict__ bcur) {
    __shared__ int sm[256];
    const int t = threadIdx.x;
    int v = (t < NBUK) ? bcnt[t] : 0;
    sm[t] = v;
    __syncthreads();
#pragma unroll
    for (int off = 1; off < 256; off <<= 1) {
        int a = (t >= off) ? sm[t - off] : 0;
        __syncthreads();
        sm[t] += a;
        __syncthreads();
    }
    if (t < NBUK) {
        int excl = sm[t] - v;
        bstart[t] = excl;
        bcur[t] = excl;
    }
    if (t == NBUK - 1) bstart[NBUK] = sm[t];   // == NE
}

// XCD-affinity over buckets; per-bucket cursor -> sequential line-combining writes.
// packedA.x = (rlocal<<17)|col, packedA.y = val bits
__global__ __launch_bounds__(256) void bucket_scatter_kernel(const int* __restrict__ rows,
                                                             const int* __restrict__ cols,
                                                             const float* __restrict__ vals,
                                                             int* __restrict__ bcur,
                                                             int2* __restrict__ packedA,
                                                             int cohort_threads) {
    const int cohort = blockIdx.x & 7;
    const int ctid = (blockIdx.x >> 3) * 256 + threadIdx.x;
    for (int e = ctid; e < NE; e += cohort_threads) {
        int r = __builtin_nontemporal_load(&rows[e]);
        int buk = r >> 9;
        if ((buk & 7) == cohort) {
            int c = __builtin_nontemporal_load(&cols[e]);
            float v = __builtin_nontemporal_load(&vals[e]);
            int pos = atomicAdd(&bcur[buk], 1);
            packedA[pos] = make_int2(((r & 511) << 17) | c, __float_as_int(v));
        }
    }
}

// one block per bucket: LDS counting sort by local row; emits rs + row-sorted packed
__global__ __launch_bounds__(256) void bucket_sort_kernel(const int* __restrict__ bstart,
                                                          const int2* __restrict__ packedA,
                                                          int2* __restrict__ packed,
                                                          int* __restrict__ rs) {
    __shared__ int2 ecopy[BUKCAP];   // 64 KB
    __shared__ int cnt512[512];
    __shared__ int off512[512];
    const int b = blockIdx.x;
    const int t = threadIdx.x;
    const int n0 = bstart[b];
    const int n1 = bstart[b + 1];
    const int cnt = n1 - n0;
    cnt512[t] = 0; cnt512[t + 256] = 0;
    __syncthreads();
    for (int i = t; i < cnt; i += 256) {
        int2 e = packedA[n0 + i];
        ecopy[i] = e;
        atomicAdd(&cnt512[e.x >> 17], 1);
    }
    __syncthreads();
    const int o1 = cnt512[t], o2 = cnt512[t + 256];
#pragma unroll
    for (int off = 1; off < 512; off <<= 1) {
        int a = (t >= off) ? cnt512[t - off] : 0;
        int a2 = (t + 256 >= off) ? cnt512[t + 256 - off] : 0;
        __syncthreads();
        cnt512[t] += a; cnt512[t + 256] += a2;
        __syncthreads();
    }
    off512[t] = cnt512[t] - o1;
    off512[t + 256] = cnt512[t + 256] - o2;
    __syncthreads();
    int row = b * 512 + t;
    if (row < NN) rs[row] = n0 + off512[t];
    int row2 = b * 512 + t + 256;
    if (row2 < NN) rs[row2] = n0 + off512[t + 256];
    if (b == NBUK - 1 && t == 0) rs[NN] = NE;
    __syncthreads();
    for (int i = t; i < cnt; i += 256) {
        int2 e = ecopy[i];
        int pos = atomicAdd(&off512[e.x >> 17], 1);
        packed[n0 + pos] = make_int2(e.x & 0x1FFFF, e.y);
    }
}

// ------------- fc0: h0 = x @ fc0_w + b (pre-ReLU, bf16) -------------
__global__ __launch_bounds__(256) void fc0_kernel(const float* __restrict__ x,
                                                  const float* __restrict__ w,
                                                  const float* __restrict__ b,
                                                  unsigned short* __restrict__ h0) {
    __shared__ float Wl[NF * NH];       // 32 KB
    __shared__ float Xt[64 * TILE_R];   // 16 KB : Xt[k][row]
    const int tid = threadIdx.x;
    {
        const float4* w4 = (const float4*)w;
        float4* wl4 = (float4*)Wl;
#pragma unroll
        for (int i = tid; i < NF * NH / 4; i += 256) wl4[i] = w4[i];
    }
    const int n0 = blockIdx.x * TILE_R;
    const int c4 = tid & 15;
    const int r4g = tid >> 4;
    const float4 bias = *(const float4*)&b[c4 * 4];
    float acc[4][4];
#pragma unroll
    for (int i = 0; i < 4; ++i) {
        acc[i][0] = bias.x; acc[i][1] = bias.y; acc[i][2] = bias.z; acc[i][3] = bias.w;
    }
    const int lrow = tid & 63;
    const int qbase = tid >> 6;
    const int grow = min(n0 + lrow, NN - 1);
    for (int kk = 0; kk < NF; kk += 64) {
        __syncthreads();
#pragma unroll
        for (int q = qbase; q < 16; q += 4) {
            f4v v = __builtin_nontemporal_load((const f4v*)&x[(size_t)grow * NF + kk + q * 4]);
            Xt[(q * 4 + 0) * 64 + lrow] = v.x;
            Xt[(q * 4 + 1) * 64 + lrow] = v.y;
            Xt[(q * 4 + 2) * 64 + lrow] = v.z;
            Xt[(q * 4 + 3) * 64 + lrow] = v.w;
        }
        __syncthreads();
#pragma unroll 8
        for (int k = 0; k < 64; ++k) {
            float4 a4 = *(const float4*)&Xt[k * 64 + r4g * 4];
            float4 w4 = *(const float4*)&Wl[(kk + k) * NH + c4 * 4];
            acc[0][0] = fmaf(a4.x, w4.x, acc[0][0]); acc[0][1] = fmaf(a4.x, w4.y, acc[0][1]);
            acc[0][2] = fmaf(a4.x, w4.z, acc[0][2]); acc[0][3] = fmaf(a4.x, w4.w, acc[0][3]);
            acc[1][0] = fmaf(a4.y, w4.x, acc[1][0]); acc[1][1] = fmaf(a4.y, w4.y, acc[1][1]);
            acc[1][2] = fmaf(a4.y, w4.z, acc[1][2]); acc[1][3] = fmaf(a4.y, w4.w, acc[1][3]);
            acc[2][0] = fmaf(a4.z, w4.x, acc[2][0]); acc[2][1] = fmaf(a4.z, w4.y, acc[2][1]);
            acc[2][2] = fmaf(a4.z, w4.z, acc[2][2]); acc[2][3] = fmaf(a4.z, w4.w, acc[2][3]);
            acc[3][0] = fmaf(a4.w, w4.x, acc[3][0]); acc[3][1] = fmaf(a4.w, w4.y, acc[3][1]);
            acc[3][2] = fmaf(a4.w, w4.z, acc[3][2]); acc[3][3] = fmaf(a4.w, w4.w, acc[3][3]);
        }
    }
#pragma unroll
    for (int i = 0; i < 4; ++i) {
        int row = n0 + r4g * 4 + i;
        if (row < NN) {
            ushort4 o = { f2bf(acc[i][0]), f2bf(acc[i][1]), f2bf(acc[i][2]), f2bf(acc[i][3]) };
            *(ushort4*)&h0[(size_t)row * NH + c4 * 4] = o;
        }
    }
}

// ------------- conv1: xw = 0.9 * relu(h0) @ W  (bf16 in/out) -------------
__global__ __launch_bounds__(256) void conv_kernel(const unsigned short* __restrict__ in_,
                                                   unsigned short* __restrict__ xw,
                                                   const float* __restrict__ w) {
    __shared__ float Wl[NH * NH];       // 16 KB
    __shared__ float Xt[64 * TILE_R];   // 16 KB
    const int tid = threadIdx.x;
    {
        const float4* w4 = (const float4*)w;
        float4* wl4 = (float4*)Wl;
#pragma unroll
        for (int i = tid; i < NH * NH / 4; i += 256) wl4[i] = w4[i];
    }
    const int n0 = blockIdx.x * TILE_R;
    const int lrow = tid & 63;
    const int qbase = tid >> 6;
    const int grow = min(n0 + lrow, NN - 1);
#pragma unroll
    for (int q = qbase; q < 16; q += 4) {
        ushort4 u = *(const ushort4*)&in_[(size_t)grow * NH + q * 4];
        Xt[(q * 4 + 0) * 64 + lrow] = fmaxf(bf2f(u.x), 0.0f);
        Xt[(q * 4 + 1) * 64 + lrow] = fmaxf(bf2f(u.y), 0.0f);
        Xt[(q * 4 + 2) * 64 + lrow] = fmaxf(bf2f(u.z), 0.0f);
        Xt[(q * 4 + 3) * 64 + lrow] = fmaxf(bf2f(u.w), 0.0f);
    }
    __syncthreads();
    const int c4 = tid & 15;
    const int r4g = tid >> 4;
    float acc[4][4];
#pragma unroll
    for (int i = 0; i < 4; ++i)
#pragma unroll
        for (int j = 0; j < 4; ++j) acc[i][j] = 0.0f;
#pragma unroll 8
    for (int k = 0; k < 64; ++k) {
        float4 a4 = *(const float4*)&Xt[k * 64 + r4g * 4];
        float4 w4 = *(const float4*)&Wl[k * NH + c4 * 4];
        acc[0][0] = fmaf(a4.x, w4.x, acc[0][0]); acc[0][1] = fmaf(a4.x, w4.y, acc[0][1]);
        acc[0][2] = fmaf(a4.x, w4.z, acc[0][2]); acc[0][3] = fmaf(a4.x, w4.w, acc[0][3]);
        acc[1][0] = fmaf(a4.y, w4.x, acc[1][0]); acc[1][1] = fmaf(a4.y, w4.y, acc[1][1]);
        acc[1][2] = fmaf(a4.y, w4.z, acc[1][2]); acc[1][3] = fmaf(a4.y, w4.w, acc[1][3]);
        acc[2][0] = fmaf(a4.z, w4.x, acc[2][0]); acc[2][1] = fmaf(a4.z, w4.y, acc[2][1]);
        acc[2][2] = fmaf(a4.z, w4.z, acc[2][2]); acc[2][3] = fmaf(a4.z, w4.w, acc[2][3]);
        acc[3][0] = fmaf(a4.w, w4.x, acc[3][0]); acc[3][1] = fmaf(a4.w, w4.y, acc[3][1]);
        acc[3][2] = fmaf(a4.w, w4.z, acc[3][2]); acc[3][3] = fmaf(a4.w, w4.w, acc[3][3]);
    }
#pragma unroll
    for (int i = 0; i < 4; ++i) {
        int row = n0 + r4g * 4 + i;
        if (row < NN) {
            ushort4 o = { f2bf(0.9f * acc[i][0]), f2bf(0.9f * acc[i][1]),
                          f2bf(0.9f * acc[i][2]), f2bf(0.9f * acc[i][3]) };
            *(ushort4*)&xw[(size_t)row * NH + c4 * 4] = o;
        }
    }
}

// ------- fused spmm+conv (layers 1-3): block = 64 rows, 4 waves x 16 rows -------
// phase1: acc row per wave-lane (gather), relu'd into transposed LDS tile
// phase2: 4x4 outer-product conv with NEXT layer W -> xw_out bf16
__global__ __launch_bounds__(256) void spmm_fused_kernel(const int* __restrict__ rs,
                                                         const int2* __restrict__ packed,
                                                         const unsigned short* __restrict__ xw_in,
                                                         const unsigned short* __restrict__ h0,
                                                         const float* __restrict__ bcurr,
                                                         const float* __restrict__ wnext,
                                                         unsigned short* __restrict__ xw_out) {
    __shared__ float Xt[64 * 68];   // [k][row] pad 68 -> 17.4 KB, 16B-aligned rows
    __shared__ float Wl[NH * NH];   // 16 KB
    const int tid = threadIdx.x;
    {
        const float4* w4 = (const float4*)wnext;
        float4* wl4 = (float4*)Wl;
#pragma unroll
        for (int i = tid; i < NH * NH / 4; i += 256) wl4[i] = w4[i];
    }
    const int lane = tid & 63;
    const int w = tid >> 6;
    const int n0 = blockIdx.x * 64;
    const float bias = bcurr[lane];
    for (int rr = 0; rr < 16; ++rr) {
        const int lr = w * 16 + rr;
        const int n = n0 + lr;
        float a = 0.0f;
        if (n < NN) {
            const int s = rs[n];
            const int e2 = rs[n + 1];
            float a0 = fmaf(0.1f, bf2f(h0[(size_t)n * NH + lane]), bias);
            float a1 = 0.0f, a2 = 0.0f, a3 = 0.0f;
            for (int base = s; base < e2; base += 64) {
                const int cntE = min(64, e2 - base);
                int2 ed = (lane < cntE) ? packed[base + lane] : make_int2(0, 0);
                int j = 0;
                for (; j + 4 <= cntE; j += 4) {
                    int c0 = __shfl(ed.x, j);
                    int c1 = __shfl(ed.x, j + 1);
                    int c2 = __shfl(ed.x, j + 2);
                    int c3 = __shfl(ed.x, j + 3);
                    float v0 = __int_as_float(__shfl(ed.y, j));
                    float v1 = __int_as_float(__shfl(ed.y, j + 1));
                    float v2 = __int_as_float(__shfl(ed.y, j + 2));
                    float v3 = __int_as_float(__shfl(ed.y, j + 3));
                    float g0 = bf2f(xw_in[(size_t)c0 * NH + lane]);
                    float g1 = bf2f(xw_in[(size_t)c1 * NH + lane]);
                    float g2 = bf2f(xw_in[(size_t)c2 * NH + lane]);
                    float g3 = bf2f(xw_in[(size_t)c3 * NH + lane]);
                    a0 = fmaf(v0, g0, a0);
                    a1 = fmaf(v1, g1, a1);
                    a2 = fmaf(v2, g2, a2);
                    a3 = fmaf(v3, g3, a3);
                }
                for (; j < cntE; ++j) {
                    int c = __shfl(ed.x, j);
                    float v = __int_as_float(__shfl(ed.y, j));
                    a0 = fmaf(v, bf2f(xw_in[(size_t)c * NH + lane]), a0);
                }
            }
            a = (a0 + a1) + (a2 + a3);
        }
        Xt[lane * 68 + lr] = fmaxf(a, 0.0f);   // relu for conv input
    }
    __syncthreads();
    const int c4 = tid & 15;
    const int r4g = tid >> 4;
    float acc[4][4];
#pragma unroll
    for (int i = 0; i < 4; ++i)
#pragma unroll
        for (int j = 0; j < 4; ++j) acc[i][j] = 0.0f;
#pragma unroll 8
    for (int k = 0; k < 64; ++k) {
        float4 a4 = *(const float4*)&Xt[k * 68 + r4g * 4];
        float4 w4 = *(const float4*)&Wl[k * NH + c4 * 4];
        acc[0][0] = fmaf(a4.x, w4.x, acc[0][0]); acc[0][1] = fmaf(a4.x, w4.y, acc[0][1]);
        acc[0][2] = fmaf(a4.x, w4.z, acc[0][2]); acc[0][3] = fmaf(a4.x, w4.w, acc[0][3]);
        acc[1][0] = fmaf(a4.y, w4.x, acc[1][0]); acc[1][1] = fmaf(a4.y, w4.y, acc[1][1]);
        acc[1][2] = fmaf(a4.y, w4.z, acc[1][2]); acc[1][3] = fmaf(a4.y, w4.w, acc[1][3]);
        acc[2][0] = fmaf(a4.z, w4.x, acc[2][0]); acc[2][1] = fmaf(a4.z, w4.y, acc[2][1]);
        acc[2][2] = fmaf(a4.z, w4.z, acc[2][2]); acc[2][3] = fmaf(a4.z, w4.w, acc[2][3]);
        acc[3][0] = fmaf(a4.w, w4.x, acc[3][0]); acc[3][1] = fmaf(a4.w, w4.y, acc[3][1]);
        acc[3][2] = fmaf(a4.w, w4.z, acc[3][2]); acc[3][3] = fmaf(a4.w, w4.w, acc[3][3]);
    }
#pragma unroll
    for (int i = 0; i < 4; ++i) {
        int row = n0 + r4g * 4 + i;
        if (row < NN) {
            ushort4 o = { f2bf(0.9f * acc[i][0]), f2bf(0.9f * acc[i][1]),
                          f2bf(0.9f * acc[i][2]), f2bf(0.9f * acc[i][3]) };
            *(ushort4*)&xw_out[(size_t)row * NH + c4 * 4] = o;
        }
    }
}

// ------- layer-4 spmm: acc fp32 out (normal store; acc reused by fc1) -------
__global__ __launch_bounds__(256) void spmm_csr_kernel(const int* __restrict__ rs,
                                                       const int2* __restrict__ packed,
                                                       const unsigned short* __restrict__ xw,
                                                       const unsigned short* __restrict__ h0,
                                                       const float* __restrict__ b,
                                                       float* __restrict__ acc,
                                                       int nwaves) {
    const int lane = threadIdx.x & 63;
    const int wid = (blockIdx.x * 256 + threadIdx.x) >> 6;
    const float bias = b[lane];
    for (int n = wid; n < NN; n += nwaves) {
        const int s = rs[n];
        const int e2 = rs[n + 1];
        float a0 = fmaf(0.1f, bf2f(h0[(size_t)n * NH + lane]), bias);
        float a1 = 0.0f, a2 = 0.0f, a3 = 0.0f;
        for (int base = s; base < e2; base += 64) {
            const int cnt = min(64, e2 - base);
            int2 ed = (lane < cnt) ? packed[base + lane] : make_int2(0, 0);
            int j = 0;
            for (; j + 4 <= cnt; j += 4) {
                int c0 = __shfl(ed.x, j);
                int c1 = __shfl(ed.x, j + 1);
                int c2 = __shfl(ed.x, j + 2);
                int c3 = __shfl(ed.x, j + 3);
                float v0 = __int_as_float(__shfl(ed.y, j));
                float v1 = __int_as_float(__shfl(ed.y, j + 1));
                float v2 = __int_as_float(__shfl(ed.y, j + 2));
                float v3 = __int_as_float(__shfl(ed.y, j + 3));
                float g0 = bf2f(xw[(size_t)c0 * NH + lane]);
                float g1 = bf2f(xw[(size_t)c1 * NH + lane]);
                float g2 = bf2f(xw[(size_t)c2 * NH + lane]);
                float g3 = bf2f(xw[(size_t)c3 * NH + lane]);
                a0 = fmaf(v0, g0, a0);
                a1 = fmaf(v1, g1, a1);
                a2 = fmaf(v2, g2, a2);
                a3 = fmaf(v3, g3, a3);
            }
            for (; j < cnt; ++j) {
                int c = __shfl(ed.x, j);
                float v = __int_as_float(__shfl(ed.y, j));
                a0 = fmaf(v, bf2f(xw[(size_t)c * NH + lane]), a0);
            }
        }
        acc[(size_t)n * NH + lane] = (a0 + a1) + (a2 + a3);
    }
}

// ------------- fc1: out = relu(in) @ fc1_w + b -------------
__global__ __launch_bounds__(256) void fc1_kernel(const float* __restrict__ in,
                                                  const float* __restrict__ w,
                                                  const float* __restrict__ b,
                                                  float* __restrict__ out) {
    __shared__ float Wl[NH * NC];       // 4 KB
    __shared__ float Xt[64 * TILE_R];   // 16 KB
    const int tid = threadIdx.x;
    for (int i = tid; i < NH * NC; i += 256) Wl[i] = w[i];
    const int n0 = blockIdx.x * TILE_R;
    const int lrow = tid & 63;
    const int qbase = tid >> 6;
    const int grow = min(n0 + lrow, NN - 1);
#pragma unroll
    for (int q = qbase; q < 16; q += 4) {
        float4 v = *(const float4*)&in[(size_t)grow * NH + q * 4];
        Xt[(q * 4 + 0) * 64 + lrow] = fmaxf(v.x, 0.0f);
        Xt[(q * 4 + 1) * 64 + lrow] = fmaxf(v.y, 0.0f);
        Xt[(q * 4 + 2) * 64 + lrow] = fmaxf(v.z, 0.0f);
        Xt[(q * 4 + 3) * 64 + lrow] = fmaxf(v.w, 0.0f);
    }
    __syncthreads();
    const int c = tid & 15;
    const int r4g = tid >> 4;
    float a0 = b[c], a1 = b[c], a2 = b[c], a3 = b[c];
#pragma unroll 8
    for (int k = 0; k < 64; ++k) {
        float4 a4 = *(const float4*)&Xt[k * 64 + r4g * 4];
        float wv = Wl[k * NC + c];
        a0 = fmaf(a4.x, wv, a0);
        a1 = fmaf(a4.y, wv, a1);
        a2 = fmaf(a4.z, wv, a2);
        a3 = fmaf(a4.w, wv, a3);
    }
    int row = n0 + r4g * 4;
    if (row + 0 < NN) out[(size_t)(row + 0) * NC + c] = a0;
    if (row + 1 < NN) out[(size_t)(row + 1) * NC + c] = a1;
    if (row + 2 < NN) out[(size_t)(row + 2) * NC + c] = a2;
    if (row + 3 < NN) out[(size_t)(row + 3) * NC + c] = a3;
}

extern "C" void kernel_launch(void* const* d_in, const int* in_sizes, int n_in,
                              void* d_out, int out_size, void* d_ws, size_t ws_size,
                              hipStream_t stream) {
    const float* x = (const float*)d_in[0];
    const int* rows = (const int*)d_in[1];
    const int* cols = (const int*)d_in[2];
    const float* vals = (const float*)d_in[3];
    const float* fc0_w = (const float*)d_in[4];
    const float* fc0_b = (const float*)d_in[5];
    const float* conv_w = (const float*)d_in[6];
    const float* conv_b = (const float*)d_in[7];
    const float* fc1_w = (const float*)d_in[8];
    const float* fc1_b = (const float*)d_in[9];
    float* out = (float*)d_out;

    char* p = (char*)d_ws;
    unsigned short* h0 = (unsigned short*)p;   p += (size_t)NN * NH * 2;   // 12.8 MB
    unsigned short* xwA = (unsigned short*)p;  p += (size_t)NN * NH * 2;   // 12.8 MB
    unsigned short* xwB = (unsigned short*)p;  p += (size_t)NN * NH * 2;   // 12.8 MB
    float* acc = (float*)p;                    p += (size_t)NN * NH * 4;   // 25.6 MB
    int2* packedA = (int2*)acc;                // alias: dead before acc is written
    int2* packed = (int2*)p;                   p += (size_t)NE * 8;        // 9.6 MB
    int* rs = (int*)p;                         p += (size_t)(NN + 1) * 4;
    int* bcnt = (int*)p;                       p += 256 * 4;
    int* bstart = (int*)p;                     p += 257 * 4;
    int* bcur = (int*)p;                       p += 256 * 4;

    const int ebl = 1200;
    const int cohort_threads = (ebl / 8) * 256;
    const int histbl = 256;

    // ---- CSR build: bucket-scatter then per-bucket counting sort ----
    init_bcnt_kernel<<<1, 256, 0, stream>>>(bcnt);
    bucket_hist_kernel<<<histbl, 256, 0, stream>>>(rows, bcnt, histbl * 256);
    bucket_scan_kernel<<<1, 256, 0, stream>>>(bcnt, bstart, bcur);
    bucket_scatter_kernel<<<ebl, 256, 0, stream>>>(rows, cols, vals, bcur, packedA, cohort_threads);
    bucket_sort_kernel<<<NBUK, 256, 0, stream>>>(bstart, packedA, packed, rs);

    // ---- dense + sparse pipeline ----
    fc0_kernel<<<NTILES, 256, 0, stream>>>(x, fc0_w, fc0_b, h0);
    conv_kernel<<<NTILES, 256, 0, stream>>>(h0, xwA, conv_w + 0 * NH * NH);

    // layers 1-3 fused (spmm + next-layer conv), ping-pong xwA/xwB
    spmm_fused_kernel<<<NTILES, 256, 0, stream>>>(rs, packed, xwA, h0,
                                                  conv_b + 0 * NH, conv_w + 1 * NH * NH, xwB);
    spmm_fused_kernel<<<NTILES, 256, 0, stream>>>(rs, packed, xwB, h0,
                                                  conv_b + 1 * NH, conv_w + 2 * NH * NH, xwA);
    spmm_fused_kernel<<<NTILES, 256, 0, stream>>>(rs, packed, xwA, h0,
                                                  conv_b + 2 * NH, conv_w + 3 * NH * NH, xwB);
    // layer 4: plain spmm -> acc fp32
    spmm_csr_kernel<<<2048, 256, 0, stream>>>(rs, packed, xwB, h0, conv_b + 3 * NH, acc, 2048 * 4);

    fc1_kernel<<<NTILES, 256, 0, stream>>>(acc, fc1_w, fc1_b, out);
}